// Round 7
// baseline (456.103 us; speedup 1.0000x reference)
//
#include <hip/hip_runtime.h>
#include <hip/hip_bf16.h>

#define NPTS 256
#define NB   4
#define KNN  27
#define EPSV 1e-5f

typedef unsigned short u16;
typedef _Float16 f16;
typedef __attribute__((ext_vector_type(8))) _Float16 f16x8;
typedef __attribute__((ext_vector_type(4))) float f32x4;

// ---------------- workspace layout (bytes); ws = 256 MiB ----------------
#define OFF_IDX    0           // 110592
#define OFF_XYZ    131072      // 4*256*32*2 = 65536   f16 [b][n][32]
#define OFF_A0     262144      // 128*32*2    = 8192
#define OFF_A1     270336      // 384*96*2    = 73728
#define OFF_A2     344064      // 1536*384*2  = 1179648
#define OFF_A3     1523712     // 6144*1536*2 = 18874368
#define OFF_A4     20398080    // 256*8160*2  = 4177920
#define OFF_PQ     24576000    // up to 4*4*6144*256*4 = 100663296 partial planes
#define OFF_XC     125239296   // 4*256*8160*2 = 16711680  f16 [b][n][8160]
#define OFF_Y      141950976   // 16*4*256*256*4 = 16777216
// end ~159 MB

__device__ __forceinline__ float f16_lo(unsigned w) {
    union { u16 u; f16 h; } c; c.u = (u16)(w & 0xffffu); return (float)c.h;
}
__device__ __forceinline__ float f16_hi(unsigned w) {
    union { u16 u; f16 h; } c; c.u = (u16)(w >> 16); return (float)c.h;
}
__device__ __forceinline__ u16 f16_bits(float f) {
    union { f16 h; u16 u; } c; c.h = (f16)f; return c.u;
}

// ---------------- kNN (+ xyz -> padded f16 [b][n][32]) ----------------
__device__ __forceinline__ float dist3_nocontract(float ax, float ay, float az,
                                                  float bx, float by, float bz) {
#pragma clang fp contract(off)
    float dx = bx - ax, dy = by - ay, dz = bz - az;
    float s = dx * dx;
    s = s + dy * dy;
    s = s + dz * dz;
    return s;
}

__global__ __launch_bounds__(64) void knn_kernel(const float* __restrict__ x,
                                                 int* __restrict__ idx,
                                                 f16* __restrict__ xyz) {
    int pt = blockIdx.x;            // 0..1023
    int b = pt >> 8, n = pt & 255;
    int lane = threadIdx.x;

    float xp0 = x[pt * 3 + 0];
    float xp1 = x[pt * 3 + 1];
    float xp2 = x[pt * 3 + 2];

    if (lane < 32) {
        float v = (lane < 3) ? x[pt * 3 + lane] : 0.f;
        xyz[((long)b * NPTS + n) * 32 + lane] = (f16)v;
    }

    unsigned long long key[4];
#pragma unroll
    for (int u = 0; u < 4; ++u) {
        int j = lane + 64 * u;
        int gj = b * NPTS + j;
        float d = dist3_nocontract(xp0, xp1, xp2,
                                   x[gj * 3 + 0], x[gj * 3 + 1], x[gj * 3 + 2]);
        key[u] = ((unsigned long long)__float_as_uint(d) << 32) | (unsigned int)j;
    }

    for (int r = 0; r < KNN; ++r) {
        unsigned long long m = key[0];
        m = key[1] < m ? key[1] : m;
        m = key[2] < m ? key[2] : m;
        m = key[3] < m ? key[3] : m;
#pragma unroll
        for (int off = 32; off; off >>= 1) {
            unsigned long long o = __shfl_xor(m, off);
            m = o < m ? o : m;
        }
        if (lane == 0) idx[pt * KNN + r] = (int)(m & 0xffffffffu);
#pragma unroll
        for (int u = 0; u < 4; ++u)
            if (key[u] == m) key[u] = ~0ULL;
    }
}

// ---------------- consolidated weight prep (all 5 matrices, one dispatch) ----
__global__ __launch_bounds__(256) void prep_all(
    const float* __restrict__ w0, const float* __restrict__ w1,
    const float* __restrict__ w2, const float* __restrict__ w3,
    const float* __restrict__ w4, char* __restrict__ ws)
{
    // cumulative block counts: 128, 512, 2048, 8192, 9216
    int bid = blockIdx.x;
    const float* w;
    int r, cbase = 0, M, Co, K, Kpad, mode;
    long offA;
    if (bid < 128)      { w = w0; r = bid;        M = 96;   Co = 48;   K = 3;    Kpad = 32;   mode = 0; offA = OFF_A0; }
    else if (bid < 512) { w = w1; r = bid - 128;  M = 384;  Co = 192;  K = 96;   Kpad = 96;   mode = 0; offA = OFF_A1; }
    else if (bid < 2048){ w = w2; r = bid - 512;  M = 1536; Co = 768;  K = 384;  Kpad = 384;  mode = 0; offA = OFF_A2; }
    else if (bid < 8192){ w = w3; r = bid - 2048; M = 6144; Co = 3072; K = 1536; Kpad = 1536; mode = 0; offA = OFF_A3; }
    else { int loc = bid - 8192; w = w4; r = loc >> 2; cbase = (loc & 3) * 2048;
           M = 256; Co = 0; K = 8160; Kpad = 8160; mode = 1; offA = OFF_A4; }

    int c0 = cbase + threadIdx.x * 8;
    if (c0 >= Kpad) return;
    f16* A = (f16*)(ws + offA);

    f16x8 hv;
#pragma unroll
    for (int j = 0; j < 8; ++j) {
        int c = c0 + j;
        float a = 0.f;
        if (c < K && r < M) {
            if (mode == 1) a = w[(long)r * K + c];
            else if (r < Co) a = w[(long)r * (2 * K) + c];
            else {
                long base = (long)(r - Co) * (2 * K);
                a = w[base + K + c] - w[base + c];
            }
        }
        hv[j] = (f16)a;
    }
    *(f16x8*)&A[(long)r * Kpad + c0] = hv;
}

// ---------------- f16 MFMA GEMM, split-K into private partial planes --------
// Block 128x128, BK=32; 4 waves 2x2; wave 64x64 = 4x4 tiles of
// mfma_f32_16x16x32_f16.
__global__ __launch_bounds__(256) void gemm_mfma(
    const f16* __restrict__ A, const f16* __restrict__ B,
    float* __restrict__ out, int M, int Kpad, int K,
    int ldF, long bsF, long bsO, int nsplit, long pstride)
{
    __shared__ u16 sA[128][40], sB[128][40];

    int bz = blockIdx.z;
    int b = bz / nsplit, slice = bz - b * nsplit;
    int kchunk = (((K + nsplit - 1) / nsplit) + 31) & ~31;
    int kstart = slice * kchunk;
    int kend = K < kstart + kchunk ? K : kstart + kchunk;

    const f16* pB = B + (long)b * bsF;
    float* Ob = out + (long)slice * pstride + (long)b * bsO;

    int m0 = blockIdx.x * 128, n0 = blockIdx.y * 128;
    int tid = threadIdx.x, lane = tid & 63, wid = tid >> 6;
    int wm = (wid >> 1) * 64, wn = (wid & 1) * 64;
    int lrow = lane & 15, quad = lane >> 4;

    int srow = tid >> 1;            // 0..127
    int sk = (tid & 1) * 16;        // 0,16

    const f16* gA = A + (long)(m0 + srow) * Kpad + sk;
    const f16* gB = pB + (long)(n0 + srow) * ldF + sk;

    f32x4 acc[4][4] = {};

    for (int kk = kstart; kk < kend; kk += 32) {
        f16x8 a0 = *(const f16x8*)(gA + kk);
        f16x8 a1 = *(const f16x8*)(gA + kk + 8);
        f16x8 b0 = *(const f16x8*)(gB + kk);
        f16x8 b1 = *(const f16x8*)(gB + kk + 8);

        __syncthreads();   // previous iteration's fragment reads complete

        *(f16x8*)&sA[srow][sk] = a0;
        *(f16x8*)&sA[srow][sk + 8] = a1;
        *(f16x8*)&sB[srow][sk] = b0;
        *(f16x8*)&sB[srow][sk + 8] = b1;

        __syncthreads();

        f16x8 fb[4];
#pragma unroll
        for (int nt = 0; nt < 4; ++nt)
            fb[nt] = *(const f16x8*)&sB[wn + nt * 16 + lrow][quad * 8];
#pragma unroll
        for (int mt = 0; mt < 4; ++mt) {
            f16x8 fa = *(const f16x8*)&sA[wm + mt * 16 + lrow][quad * 8];
#pragma unroll
            for (int nt = 0; nt < 4; ++nt)
                acc[mt][nt] = __builtin_amdgcn_mfma_f32_16x16x32_f16(fa, fb[nt], acc[mt][nt], 0, 0, 0);
        }
    }

    // epilogue: C/D layout col=lane&15, row=quad*4+reg  [m89-verified]
#pragma unroll
    for (int mt = 0; mt < 4; ++mt)
#pragma unroll
        for (int nt = 0; nt < 4; ++nt) {
            int C = n0 + wn + nt * 16 + lrow;
            int Rb = m0 + wm + mt * 16 + quad * 4;
#pragma unroll
            for (int r = 0; r < 4; ++r) {
                int R = Rb + r;
                if (R < M) Ob[(long)R * NPTS + C] = acc[mt][nt][r];
            }
        }
}

// ---------------- fused gather + stats + BN/lrelu + tp + transpose ----------
// Block = 4 consecutive channels (o0..o0+3) x all 4 batches (1 wave each).
// P packed as f16x4 (4 channels) per point in LDS -> 1 ds_read_b64 per (k)
// serves 4 channels. h = f32(f16(P)) + f32(f16-free Q) in fp32.
// Writes xc[b][n][offc+o0..+3] (val) and xc[b][n][offc+Co+o0..+3] (tp) directly.
__global__ __launch_bounds__(256) void gather_finalize(
    const float* __restrict__ PQ, long pstride, int nsplit,
    const int* __restrict__ idx,
    const float* __restrict__ g, const float* __restrict__ beta,
    f16* __restrict__ xc, int Co, int offc)
{
    __shared__ uint2 p2[NB][NPTS];      // packed f16x4 P, 8 KB
    __shared__ uint2 val2[NB][NPTS];    // packed f16x4 val, 8 KB
    __shared__ float red[NB][8];
    int o0 = blockIdx.x * 4;
    int b = threadIdx.x >> 6;
    int lane = threadIdx.x & 63;

    float qv[4][4];                     // [c][u]
#pragma unroll
    for (int u = 0; u < 4; ++u) {
        int n = lane + 64 * u;
        u16 ph[4];
#pragma unroll
        for (int c = 0; c < 4; ++c) {
            long rp = ((long)b * 2 * Co + o0 + c) * NPTS + n;
            long rq = rp + (long)Co * NPTS;
            float pv = 0.f, q = 0.f;
            for (int s = 0; s < nsplit; ++s) {
                pv += PQ[s * pstride + rp];
                q += PQ[s * pstride + rq];
            }
            ph[c] = f16_bits(pv);
            qv[c][u] = q;
        }
        uint2 pk;
        pk.x = (unsigned)ph[0] | ((unsigned)ph[1] << 16);
        pk.y = (unsigned)ph[2] | ((unsigned)ph[3] << 16);
        p2[b][n] = pk;
    }
    __syncthreads();

    float s[4] = {}, ss[4] = {};
    float mx[4][4], mn[4][4];
#pragma unroll
    for (int c = 0; c < 4; ++c)
#pragma unroll
        for (int u = 0; u < 4; ++u) { mx[c][u] = -__builtin_inff(); mn[c][u] = __builtin_inff(); }

#pragma unroll
    for (int u = 0; u < 4; ++u) {
        int n = lane + 64 * u;
        const int* ip = idx + ((long)b * NPTS + n) * KNN;
#pragma unroll
        for (int k = 0; k < KNN; ++k) {
            uint2 w = p2[b][ip[k]];
            float h0 = f16_lo(w.x) + qv[0][u];
            float h1 = f16_hi(w.x) + qv[1][u];
            float h2 = f16_lo(w.y) + qv[2][u];
            float h3 = f16_hi(w.y) + qv[3][u];
            s[0] += h0; ss[0] += h0 * h0; mx[0][u] = fmaxf(mx[0][u], h0); mn[0][u] = fminf(mn[0][u], h0);
            s[1] += h1; ss[1] += h1 * h1; mx[1][u] = fmaxf(mx[1][u], h1); mn[1][u] = fminf(mn[1][u], h1);
            s[2] += h2; ss[2] += h2 * h2; mx[2][u] = fmaxf(mx[2][u], h2); mn[2][u] = fminf(mn[2][u], h2);
            s[3] += h3; ss[3] += h3 * h3; mx[3][u] = fmaxf(mx[3][u], h3); mn[3][u] = fminf(mn[3][u], h3);
        }
    }
#pragma unroll
    for (int c = 0; c < 4; ++c)
#pragma unroll
        for (int off = 32; off; off >>= 1) {
            s[c] += __shfl_xor(s[c], off);
            ss[c] += __shfl_xor(ss[c], off);
        }
    if (lane < 4) { red[b][lane] = s[lane]; red[b][4 + lane] = ss[lane]; }
    __syncthreads();

    const float cnt = (float)(NB * NPTS * KNN);
    float sc[4], tt[4];
#pragma unroll
    for (int c = 0; c < 4; ++c) {
        float ts = (red[0][c] + red[1][c]) + (red[2][c] + red[3][c]);
        float tss = (red[0][4 + c] + red[1][4 + c]) + (red[2][4 + c] + red[3][4 + c]);
        float mean = ts / cnt;
        float var = tss / cnt - mean * mean;
        sc[c] = g[o0 + c] * (1.0f / sqrtf(var + EPSV));
        tt[c] = beta[o0 + c] - mean * sc[c];
    }

#pragma unroll
    for (int u = 0; u < 4; ++u) {
        int n = lane + 64 * u;
        u16 vh[4];
#pragma unroll
        for (int c = 0; c < 4; ++c) {
            float v = (sc[c] >= 0.f) ? mx[c][u] : mn[c][u];
            float z = sc[c] * v + tt[c];
            z = z >= 0.f ? z : 0.2f * z;
            vh[c] = f16_bits(z);
        }
        uint2 pk;
        pk.x = (unsigned)vh[0] | ((unsigned)vh[1] << 16);
        pk.y = (unsigned)vh[2] | ((unsigned)vh[3] << 16);
        val2[b][n] = pk;
    }
    __syncthreads();

#pragma unroll
    for (int u = 0; u < 4; ++u) {
        int n = lane + 64 * u;
        uint2 v0 = val2[0][n], v1 = val2[1][n];
        u16 th[4];
        th[0] = f16_bits(0.5f * (f16_lo(v0.x) + f16_lo(v1.x)));
        th[1] = f16_bits(0.5f * (f16_hi(v0.x) + f16_hi(v1.x)));
        th[2] = f16_bits(0.5f * (f16_lo(v0.y) + f16_lo(v1.y)));
        th[3] = f16_bits(0.5f * (f16_hi(v0.y) + f16_hi(v1.y)));
        uint2 tp;
        tp.x = (unsigned)th[0] | ((unsigned)th[1] << 16);
        tp.y = (unsigned)th[2] | ((unsigned)th[3] << 16);
        long base = ((long)b * NPTS + n) * 8160;
        *(uint2*)&xc[base + offc + o0] = val2[b][n];
        *(uint2*)&xc[base + offc + Co + o0] = tp;
    }
}

// ---------------- final BN + lrelu -> fp32 out (sums 16 partial y planes) ---
__global__ __launch_bounds__(256) void final_bn(const float* __restrict__ y,
                                                const float* __restrict__ g4,
                                                const float* __restrict__ b4,
                                                float* __restrict__ out) {
    __shared__ float red[8];
    int o = blockIdx.x;
    int tid = threadIdx.x;
    int lane = tid & 63, w = tid >> 6;

    float v[4];
    float s = 0.f, ss = 0.f;
#pragma unroll
    for (int b = 0; b < 4; ++b) {
        float acc = 0.f;
#pragma unroll
        for (int sp = 0; sp < 16; ++sp)
            acc += y[sp * 262144 + b * 65536 + o * 256 + tid];
        v[b] = acc;
        s += acc;
        ss += acc * acc;
    }
#pragma unroll
    for (int off = 32; off; off >>= 1) {
        s += __shfl_xor(s, off);
        ss += __shfl_xor(ss, off);
    }
    if (lane == 0) { red[w] = s; red[4 + w] = ss; }
    __syncthreads();
    s = (red[0] + red[1]) + (red[2] + red[3]);
    ss = (red[4] + red[5]) + (red[6] + red[7]);
    float mean = s / 1024.f;
    float var = ss / 1024.f - mean * mean;
    float sc = g4[o] * (1.0f / sqrtf(var + EPSV));
    float tt = b4[o] - mean * sc;
#pragma unroll
    for (int b = 0; b < 4; ++b) {
        float z = sc * v[b] + tt;
        z = z >= 0.f ? z : 0.2f * z;
        out[(long)b * 65536 + o * 256 + tid] = z;
    }
}

// ---------------- launch ----------------
extern "C" void kernel_launch(void* const* d_in, const int* in_sizes, int n_in,
                              void* d_out, int out_size, void* d_ws, size_t ws_size,
                              hipStream_t stream) {
    const float* x = (const float*)d_in[0];
    const float* wl[4];
    const float* gl[4];
    const float* bl[4];
    for (int i = 0; i < 4; ++i) {
        wl[i] = (const float*)d_in[1 + 3 * i];
        gl[i] = (const float*)d_in[2 + 3 * i];
        bl[i] = (const float*)d_in[3 + 3 * i];
    }
    const float* w4 = (const float*)d_in[13];
    const float* g4 = (const float*)d_in[14];
    const float* b4 = (const float*)d_in[15];

    char* ws = (char*)d_ws;
    int* idx = (int*)(ws + OFF_IDX);
    f16* xyz = (f16*)(ws + OFF_XYZ);
    float* PQ = (float*)(ws + OFF_PQ);
    f16* xc = (f16*)(ws + OFF_XC);
    float* y = (float*)(ws + OFF_Y);

    knn_kernel<<<dim3(NB * NPTS), dim3(64), 0, stream>>>(x, idx, xyz);
    prep_all<<<dim3(9216), dim3(256), 0, stream>>>(wl[0], wl[1], wl[2], wl[3], w4, ws);

    const int Kp[4] = {32, 96, 384, 1536};     // padded K (multiples of 32)
    const int Co[4] = {48, 192, 768, 3072};
    const int offc[4] = {0, 96, 480, 2016};
    const int inoff[4] = {0, 0, 96, 480};
    const int nsp[4] = {1, 3, 4, 3};
    const long aoff[4] = {OFF_A0, OFF_A1, OFF_A2, OFF_A3};

    for (int i = 0; i < 4; ++i) {
        int M = 2 * Co[i];
        int Mpad = (M + 127) & ~127;
        const f16* A = (const f16*)(ws + aoff[i]);

        const f16* Bp;
        int ldF;
        long bsF;
        if (i == 0) { Bp = xyz; ldF = 32; bsF = (long)NPTS * 32; }
        else { Bp = xc + inoff[i]; ldF = 8160; bsF = (long)NPTS * 8160; }

        long pstride = (long)NB * M * NPTS;   // one partial plane
        gemm_mfma<<<dim3(Mpad / 128, NPTS / 128, NB * nsp[i]), dim3(256), 0, stream>>>(
            A, Bp, PQ, M, Kp[i], Kp[i], ldF, bsF, (long)M * NPTS, nsp[i], pstride);

        gather_finalize<<<dim3(Co[i] / 4), dim3(256), 0, stream>>>(
            PQ, pstride, nsp[i], idx, gl[i], bl[i], xc, Co[i], offc[i]);
    }

    // final projection: split-K=16 into 16 private y planes, summed in final_bn
    gemm_mfma<<<dim3(2, 2, NB * 16), dim3(256), 0, stream>>>(
        (const f16*)(ws + OFF_A4), xc, y, 256, 8160, 8160, 8160,
        (long)NPTS * 8160, (long)256 * NPTS, 16, (long)NB * 256 * NPTS);
    final_bn<<<dim3(256), dim3(256), 0, stream>>>(y, g4, b4, (float*)d_out);
}

// Round 8
// 359.519 us; speedup vs baseline: 1.2686x; 1.2686x over previous
//
#include <hip/hip_runtime.h>
#include <hip/hip_bf16.h>

#define NPTS 256
#define NB   4
#define KNN  27
#define EPSV 1e-5f

typedef unsigned short u16;
typedef _Float16 f16;
typedef __attribute__((ext_vector_type(8))) _Float16 f16x8;
typedef __attribute__((ext_vector_type(4))) float f32x4;

// ---------------- workspace layout (bytes); ws = 256 MiB ----------------
#define OFF_IDX    0           // 110592
#define OFF_XYZ    131072      // 4*256*32*2 = 65536   f16 [b][n][32]
#define OFF_A0     262144      // 128*32*2    = 8192
#define OFF_A1     270336      // 384*96*2    = 73728
#define OFF_A2     344064      // 1536*384*2  = 1179648
#define OFF_A3     1523712     // 6144*1536*2 = 18874368
#define OFF_A4     20398080    // 256*8160*2  = 4177920
#define OFF_PQ     24576000    // 3*4*6144*256*4 = 75497472 partial planes
#define OFF_SLICE  100073472   // 4*6144*256*4 = 25165824 fp32 [b][2Co][n]
#define OFF_XC     125239296   // 4*256*8160*2 = 16711680  f16 [b][n][8160]
#define OFF_Y      141950976   // 16*4*256*256*4 = 16777216
// end ~151 MB

__device__ __forceinline__ float f16_lo(unsigned w) {
    union { u16 u; f16 h; } c; c.u = (u16)(w & 0xffffu); return (float)c.h;
}
__device__ __forceinline__ float f16_hi(unsigned w) {
    union { u16 u; f16 h; } c; c.u = (u16)(w >> 16); return (float)c.h;
}
__device__ __forceinline__ u16 f16_bits(float f) {
    union { f16 h; u16 u; } c; c.h = (f16)f; return c.u;
}

// ---------------- kNN (+ xyz -> padded f16 [b][n][32]) ----------------
__device__ __forceinline__ float dist3_nocontract(float ax, float ay, float az,
                                                  float bx, float by, float bz) {
#pragma clang fp contract(off)
    float dx = bx - ax, dy = by - ay, dz = bz - az;
    float s = dx * dx;
    s = s + dy * dy;
    s = s + dz * dz;
    return s;
}

__global__ __launch_bounds__(64) void knn_kernel(const float* __restrict__ x,
                                                 int* __restrict__ idx,
                                                 f16* __restrict__ xyz) {
    int pt = blockIdx.x;            // 0..1023
    int b = pt >> 8, n = pt & 255;
    int lane = threadIdx.x;

    float xp0 = x[pt * 3 + 0];
    float xp1 = x[pt * 3 + 1];
    float xp2 = x[pt * 3 + 2];

    if (lane < 32) {
        float v = (lane < 3) ? x[pt * 3 + lane] : 0.f;
        xyz[((long)b * NPTS + n) * 32 + lane] = (f16)v;
    }

    unsigned long long key[4];
#pragma unroll
    for (int u = 0; u < 4; ++u) {
        int j = lane + 64 * u;
        int gj = b * NPTS + j;
        float d = dist3_nocontract(xp0, xp1, xp2,
                                   x[gj * 3 + 0], x[gj * 3 + 1], x[gj * 3 + 2]);
        key[u] = ((unsigned long long)__float_as_uint(d) << 32) | (unsigned int)j;
    }

    for (int r = 0; r < KNN; ++r) {
        unsigned long long m = key[0];
        m = key[1] < m ? key[1] : m;
        m = key[2] < m ? key[2] : m;
        m = key[3] < m ? key[3] : m;
#pragma unroll
        for (int off = 32; off; off >>= 1) {
            unsigned long long o = __shfl_xor(m, off);
            m = o < m ? o : m;
        }
        if (lane == 0) idx[pt * KNN + r] = (int)(m & 0xffffffffu);
#pragma unroll
        for (int u = 0; u < 4; ++u)
            if (key[u] == m) key[u] = ~0ULL;
    }
}

// ---------------- consolidated weight prep (all 5 matrices, one dispatch) ----
__global__ __launch_bounds__(256) void prep_all(
    const float* __restrict__ w0, const float* __restrict__ w1,
    const float* __restrict__ w2, const float* __restrict__ w3,
    const float* __restrict__ w4, char* __restrict__ ws)
{
    // cumulative block counts: 128, 512, 2048, 8192, 9216
    int bid = blockIdx.x;
    const float* w;
    int r, cbase = 0, M, Co, K, Kpad, mode;
    long offA;
    if (bid < 128)      { w = w0; r = bid;        M = 96;   Co = 48;   K = 3;    Kpad = 32;   mode = 0; offA = OFF_A0; }
    else if (bid < 512) { w = w1; r = bid - 128;  M = 384;  Co = 192;  K = 96;   Kpad = 96;   mode = 0; offA = OFF_A1; }
    else if (bid < 2048){ w = w2; r = bid - 512;  M = 1536; Co = 768;  K = 384;  Kpad = 384;  mode = 0; offA = OFF_A2; }
    else if (bid < 8192){ w = w3; r = bid - 2048; M = 6144; Co = 3072; K = 1536; Kpad = 1536; mode = 0; offA = OFF_A3; }
    else { int loc = bid - 8192; w = w4; r = loc >> 2; cbase = (loc & 3) * 2048;
           M = 256; Co = 0; K = 8160; Kpad = 8160; mode = 1; offA = OFF_A4; }

    int c0 = cbase + threadIdx.x * 8;
    if (c0 >= Kpad) return;
    f16* A = (f16*)(ws + offA);

    f16x8 hv;
#pragma unroll
    for (int j = 0; j < 8; ++j) {
        int c = c0 + j;
        float a = 0.f;
        if (c < K && r < M) {
            if (mode == 1) a = w[(long)r * K + c];
            else if (r < Co) a = w[(long)r * (2 * K) + c];
            else {
                long base = (long)(r - Co) * (2 * K);
                a = w[base + K + c] - w[base + c];
            }
        }
        hv[j] = (f16)a;
    }
    *(f16x8*)&A[(long)r * Kpad + c0] = hv;
}

// ---------------- f16 MFMA GEMM, split-K into private partial planes --------
// Block 128x128, BK=32; 4 waves 2x2; wave 64x64 = 4x4 tiles of
// mfma_f32_16x16x32_f16.
__global__ __launch_bounds__(256) void gemm_mfma(
    const f16* __restrict__ A, const f16* __restrict__ B,
    float* __restrict__ out, int M, int Kpad, int K,
    int ldF, long bsF, long bsO, int nsplit, long pstride)
{
    __shared__ u16 sA[128][40], sB[128][40];

    int bz = blockIdx.z;
    int b = bz / nsplit, slice = bz - b * nsplit;
    int kchunk = (((K + nsplit - 1) / nsplit) + 31) & ~31;
    int kstart = slice * kchunk;
    int kend = K < kstart + kchunk ? K : kstart + kchunk;

    const f16* pB = B + (long)b * bsF;
    float* Ob = out + (long)slice * pstride + (long)b * bsO;

    int m0 = blockIdx.x * 128, n0 = blockIdx.y * 128;
    int tid = threadIdx.x, lane = tid & 63, wid = tid >> 6;
    int wm = (wid >> 1) * 64, wn = (wid & 1) * 64;
    int lrow = lane & 15, quad = lane >> 4;

    int srow = tid >> 1;            // 0..127
    int sk = (tid & 1) * 16;        // 0,16

    const f16* gA = A + (long)(m0 + srow) * Kpad + sk;
    const f16* gB = pB + (long)(n0 + srow) * ldF + sk;

    f32x4 acc[4][4] = {};

    for (int kk = kstart; kk < kend; kk += 32) {
        f16x8 a0 = *(const f16x8*)(gA + kk);
        f16x8 a1 = *(const f16x8*)(gA + kk + 8);
        f16x8 b0 = *(const f16x8*)(gB + kk);
        f16x8 b1 = *(const f16x8*)(gB + kk + 8);

        __syncthreads();   // previous iteration's fragment reads complete

        *(f16x8*)&sA[srow][sk] = a0;
        *(f16x8*)&sA[srow][sk + 8] = a1;
        *(f16x8*)&sB[srow][sk] = b0;
        *(f16x8*)&sB[srow][sk + 8] = b1;

        __syncthreads();

        f16x8 fb[4];
#pragma unroll
        for (int nt = 0; nt < 4; ++nt)
            fb[nt] = *(const f16x8*)&sB[wn + nt * 16 + lrow][quad * 8];
#pragma unroll
        for (int mt = 0; mt < 4; ++mt) {
            f16x8 fa = *(const f16x8*)&sA[wm + mt * 16 + lrow][quad * 8];
#pragma unroll
            for (int nt = 0; nt < 4; ++nt)
                acc[mt][nt] = __builtin_amdgcn_mfma_f32_16x16x32_f16(fa, fb[nt], acc[mt][nt], 0, 0, 0);
        }
    }

    // epilogue: C/D layout col=lane&15, row=quad*4+reg  [m89-verified]
#pragma unroll
    for (int mt = 0; mt < 4; ++mt)
#pragma unroll
        for (int nt = 0; nt < 4; ++nt) {
            int C = n0 + wn + nt * 16 + lrow;
            int Rb = m0 + wm + mt * 16 + quad * 4;
#pragma unroll
            for (int r = 0; r < 4; ++r) {
                int R = Rb + r;
                if (R < M) Ob[(long)R * NPTS + C] = acc[mt][nt][r];
            }
        }
}

// ---------------- fused gather + stats + BN/lrelu + tp concat ---------------
// Block = 4 consecutive channels (o0..o0+3) x 4 batches (1 wave each).
// P for 4 channels packed as f16x4 per point in LDS -> 1 ds_read_b64 per k
// serves 4 channels. u-loop rolled; per-u max/min stashed packed in LDS to
// keep VGPR low (R7 post-mortem: 256 VGPR -> 10% occupancy).
// Writes val and tp rows to slice fp32 [b][2Co][n] (n-contiguous, coalesced);
// transpose_cn does the [c][n] -> [n][c] f16 conversion.
__global__ __launch_bounds__(256, 4) void gather_finalize(
    const float* __restrict__ PQ, long pstride, int nsplit,
    const int* __restrict__ idx,
    const float* __restrict__ g, const float* __restrict__ beta,
    float* __restrict__ slice, int Co)
{
    __shared__ uint2 p2[NB][NPTS];      // packed f16x4 P, 8 KB
    __shared__ uint2 mxs[NB][NPTS];     // packed f16x4 per-n max, 8 KB
    __shared__ uint2 mns[NB][NPTS];     // packed f16x4 per-n min, 8 KB
    __shared__ uint2 vals[NB][NPTS];    // packed f16x4 val, 8 KB
    __shared__ float red[NB][8];
    int o0 = blockIdx.x * 4;
    int b = threadIdx.x >> 6;
    int lane = threadIdx.x & 63;

    long base_p = ((long)b * 2 * Co + o0) * NPTS;   // channel o0 P row
    long base_q = base_p + (long)Co * NPTS;         // channel o0 Q row

#pragma unroll 1
    for (int u = 0; u < 4; ++u) {
        int n = lane + 64 * u;
        u16 ph[4];
#pragma unroll
        for (int c = 0; c < 4; ++c) {
            float pv = 0.f;
            for (int sp = 0; sp < nsplit; ++sp)
                pv += PQ[sp * pstride + base_p + c * NPTS + n];
            ph[c] = f16_bits(pv);
        }
        uint2 pk;
        pk.x = (unsigned)ph[0] | ((unsigned)ph[1] << 16);
        pk.y = (unsigned)ph[2] | ((unsigned)ph[3] << 16);
        p2[b][n] = pk;
    }
    __syncthreads();

    float s0 = 0.f, s1 = 0.f, s2 = 0.f, s3 = 0.f;
    float t0 = 0.f, t1 = 0.f, t2 = 0.f, t3 = 0.f;
#pragma unroll 1
    for (int u = 0; u < 4; ++u) {
        int n = lane + 64 * u;
        float q0 = 0.f, q1 = 0.f, q2 = 0.f, q3 = 0.f;
        for (int sp = 0; sp < nsplit; ++sp) {
            const float* Qp = PQ + sp * pstride + base_q + n;
            q0 += Qp[0];
            q1 += Qp[NPTS];
            q2 += Qp[2 * NPTS];
            q3 += Qp[3 * NPTS];
        }
        float mx0 = -__builtin_inff(), mx1 = mx0, mx2 = mx0, mx3 = mx0;
        float mn0 = __builtin_inff(), mn1 = mn0, mn2 = mn0, mn3 = mn0;
        const int* ip = idx + ((long)b * NPTS + n) * KNN;
#pragma unroll
        for (int k = 0; k < KNN; ++k) {
            uint2 w = p2[b][ip[k]];
            float h0 = f16_lo(w.x) + q0;
            float h1 = f16_hi(w.x) + q1;
            float h2 = f16_lo(w.y) + q2;
            float h3 = f16_hi(w.y) + q3;
            s0 += h0; t0 += h0 * h0; mx0 = fmaxf(mx0, h0); mn0 = fminf(mn0, h0);
            s1 += h1; t1 += h1 * h1; mx1 = fmaxf(mx1, h1); mn1 = fminf(mn1, h1);
            s2 += h2; t2 += h2 * h2; mx2 = fmaxf(mx2, h2); mn2 = fminf(mn2, h2);
            s3 += h3; t3 += h3 * h3; mx3 = fmaxf(mx3, h3); mn3 = fminf(mn3, h3);
        }
        uint2 mk, nk;
        mk.x = (unsigned)f16_bits(mx0) | ((unsigned)f16_bits(mx1) << 16);
        mk.y = (unsigned)f16_bits(mx2) | ((unsigned)f16_bits(mx3) << 16);
        nk.x = (unsigned)f16_bits(mn0) | ((unsigned)f16_bits(mn1) << 16);
        nk.y = (unsigned)f16_bits(mn2) | ((unsigned)f16_bits(mn3) << 16);
        mxs[b][n] = mk;
        mns[b][n] = nk;
    }
#pragma unroll
    for (int off = 32; off; off >>= 1) {
        s0 += __shfl_xor(s0, off); t0 += __shfl_xor(t0, off);
        s1 += __shfl_xor(s1, off); t1 += __shfl_xor(t1, off);
        s2 += __shfl_xor(s2, off); t2 += __shfl_xor(t2, off);
        s3 += __shfl_xor(s3, off); t3 += __shfl_xor(t3, off);
    }
    if (lane == 0) {
        red[b][0] = s0; red[b][1] = s1; red[b][2] = s2; red[b][3] = s3;
        red[b][4] = t0; red[b][5] = t1; red[b][6] = t2; red[b][7] = t3;
    }
    __syncthreads();

    const float cnt = (float)(NB * NPTS * KNN);
    float sc[4], tt[4];
#pragma unroll
    for (int c = 0; c < 4; ++c) {
        float ts = (red[0][c] + red[1][c]) + (red[2][c] + red[3][c]);
        float tss = (red[0][4 + c] + red[1][4 + c]) + (red[2][4 + c] + red[3][4 + c]);
        float mean = ts / cnt;
        float var = tss / cnt - mean * mean;
        sc[c] = g[o0 + c] * (1.0f / sqrtf(var + EPSV));
        tt[c] = beta[o0 + c] - mean * sc[c];
    }

#pragma unroll 1
    for (int u = 0; u < 4; ++u) {
        int n = lane + 64 * u;
        uint2 mk = mxs[b][n], nk = mns[b][n];
        float e0 = (sc[0] >= 0.f) ? f16_lo(mk.x) : f16_lo(nk.x);
        float e1 = (sc[1] >= 0.f) ? f16_hi(mk.x) : f16_hi(nk.x);
        float e2 = (sc[2] >= 0.f) ? f16_lo(mk.y) : f16_lo(nk.y);
        float e3 = (sc[3] >= 0.f) ? f16_hi(mk.y) : f16_hi(nk.y);
        float z0 = sc[0] * e0 + tt[0]; z0 = z0 >= 0.f ? z0 : 0.2f * z0;
        float z1 = sc[1] * e1 + tt[1]; z1 = z1 >= 0.f ? z1 : 0.2f * z1;
        float z2 = sc[2] * e2 + tt[2]; z2 = z2 >= 0.f ? z2 : 0.2f * z2;
        float z3 = sc[3] * e3 + tt[3]; z3 = z3 >= 0.f ? z3 : 0.2f * z3;
        slice[base_p + 0 * NPTS + n] = z0;
        slice[base_p + 1 * NPTS + n] = z1;
        slice[base_p + 2 * NPTS + n] = z2;
        slice[base_p + 3 * NPTS + n] = z3;
        uint2 vk;
        vk.x = (unsigned)f16_bits(z0) | ((unsigned)f16_bits(z1) << 16);
        vk.y = (unsigned)f16_bits(z2) | ((unsigned)f16_bits(z3) << 16);
        vals[b][n] = vk;
    }
    __syncthreads();

#pragma unroll 1
    for (int u = 0; u < 4; ++u) {
        int n = lane + 64 * u;
        uint2 v0 = vals[0][n], v1 = vals[1][n];
        slice[base_q + 0 * NPTS + n] = 0.5f * (f16_lo(v0.x) + f16_lo(v1.x));
        slice[base_q + 1 * NPTS + n] = 0.5f * (f16_hi(v0.x) + f16_hi(v1.x));
        slice[base_q + 2 * NPTS + n] = 0.5f * (f16_lo(v0.y) + f16_lo(v1.y));
        slice[base_q + 3 * NPTS + n] = 0.5f * (f16_hi(v0.y) + f16_hi(v1.y));
    }
}

// ---------------- transpose [b][C][n] -> f16 [b][n][8160] at offc ----------
__global__ __launch_bounds__(256) void transpose_cn(
    const float* __restrict__ slice, f16* __restrict__ xc,
    int Ctot, int offc)
{
    __shared__ float t[32][33];
    int c0 = blockIdx.x * 32, n0 = blockIdx.y * 32, b = blockIdx.z;
    const float* S = slice + (long)b * Ctot * NPTS;
    int tid = threadIdx.x;
    int r = tid >> 3, s4 = (tid & 7) * 4;

    f32x4 v = *(const f32x4*)&S[(long)(c0 + r) * NPTS + n0 + s4];
    t[r][s4 + 0] = v[0];
    t[r][s4 + 1] = v[1];
    t[r][s4 + 2] = v[2];
    t[r][s4 + 3] = v[3];
    __syncthreads();

    long base = ((long)b * NPTS + n0 + r) * 8160 + offc + c0 + s4;
    typedef __attribute__((ext_vector_type(4))) _Float16 f16x4;
    f16x4 hv;
#pragma unroll
    for (int j = 0; j < 4; ++j) hv[j] = (f16)t[s4 + j][r];
    *(f16x4*)&xc[base] = hv;
}

// ---------------- final BN + lrelu -> fp32 out (sums 16 partial y planes) ---
__global__ __launch_bounds__(256) void final_bn(const float* __restrict__ y,
                                                const float* __restrict__ g4,
                                                const float* __restrict__ b4,
                                                float* __restrict__ out) {
    __shared__ float red[8];
    int o = blockIdx.x;
    int tid = threadIdx.x;
    int lane = tid & 63, w = tid >> 6;

    float v[4];
    float s = 0.f, ss = 0.f;
#pragma unroll
    for (int b = 0; b < 4; ++b) {
        float acc = 0.f;
#pragma unroll
        for (int sp = 0; sp < 16; ++sp)
            acc += y[sp * 262144 + b * 65536 + o * 256 + tid];
        v[b] = acc;
        s += acc;
        ss += acc * acc;
    }
#pragma unroll
    for (int off = 32; off; off >>= 1) {
        s += __shfl_xor(s, off);
        ss += __shfl_xor(ss, off);
    }
    if (lane == 0) { red[w] = s; red[4 + w] = ss; }
    __syncthreads();
    s = (red[0] + red[1]) + (red[2] + red[3]);
    ss = (red[4] + red[5]) + (red[6] + red[7]);
    float mean = s / 1024.f;
    float var = ss / 1024.f - mean * mean;
    float sc = g4[o] * (1.0f / sqrtf(var + EPSV));
    float tt = b4[o] - mean * sc;
#pragma unroll
    for (int b = 0; b < 4; ++b) {
        float z = sc * v[b] + tt;
        z = z >= 0.f ? z : 0.2f * z;
        out[(long)b * 65536 + o * 256 + tid] = z;
    }
}

// ---------------- launch ----------------
extern "C" void kernel_launch(void* const* d_in, const int* in_sizes, int n_in,
                              void* d_out, int out_size, void* d_ws, size_t ws_size,
                              hipStream_t stream) {
    const float* x = (const float*)d_in[0];
    const float* wl[4];
    const float* gl[4];
    const float* bl[4];
    for (int i = 0; i < 4; ++i) {
        wl[i] = (const float*)d_in[1 + 3 * i];
        gl[i] = (const float*)d_in[2 + 3 * i];
        bl[i] = (const float*)d_in[3 + 3 * i];
    }
    const float* w4 = (const float*)d_in[13];
    const float* g4 = (const float*)d_in[14];
    const float* b4 = (const float*)d_in[15];

    char* ws = (char*)d_ws;
    int* idx = (int*)(ws + OFF_IDX);
    f16* xyz = (f16*)(ws + OFF_XYZ);
    float* PQ = (float*)(ws + OFF_PQ);
    float* slice = (float*)(ws + OFF_SLICE);
    f16* xc = (f16*)(ws + OFF_XC);
    float* y = (float*)(ws + OFF_Y);

    knn_kernel<<<dim3(NB * NPTS), dim3(64), 0, stream>>>(x, idx, xyz);
    prep_all<<<dim3(9216), dim3(256), 0, stream>>>(wl[0], wl[1], wl[2], wl[3], w4, ws);

    const int Kp[4] = {32, 96, 384, 1536};     // padded K (multiples of 32)
    const int Co[4] = {48, 192, 768, 3072};
    const int offc[4] = {0, 96, 480, 2016};
    const int inoff[4] = {0, 0, 96, 480};
    const int nsp[4] = {1, 3, 4, 3};
    const long aoff[4] = {OFF_A0, OFF_A1, OFF_A2, OFF_A3};

    for (int i = 0; i < 4; ++i) {
        int M = 2 * Co[i];
        int Mpad = (M + 127) & ~127;
        const f16* A = (const f16*)(ws + aoff[i]);

        const f16* Bp;
        int ldF;
        long bsF;
        if (i == 0) { Bp = xyz; ldF = 32; bsF = (long)NPTS * 32; }
        else { Bp = xc + inoff[i]; ldF = 8160; bsF = (long)NPTS * 8160; }

        long pstride = (long)NB * M * NPTS;   // one partial plane
        gemm_mfma<<<dim3(Mpad / 128, NPTS / 128, NB * nsp[i]), dim3(256), 0, stream>>>(
            A, Bp, PQ, M, Kp[i], Kp[i], ldF, bsF, (long)M * NPTS, nsp[i], pstride);

        gather_finalize<<<dim3(Co[i] / 4), dim3(256), 0, stream>>>(
            PQ, pstride, nsp[i], idx, gl[i], bl[i], slice, Co[i]);
        transpose_cn<<<dim3(M / 32, NPTS / 32, NB), dim3(256), 0, stream>>>(
            slice, xc, M, offc[i]);
    }

    // final projection: split-K=16 into 16 private y planes, summed in final_bn
    gemm_mfma<<<dim3(2, 2, NB * 16), dim3(256), 0, stream>>>(
        (const f16*)(ws + OFF_A4), xc, y, 256, 8160, 8160, 8160,
        (long)NPTS * 8160, (long)256 * NPTS, 16, (long)NB * 256 * NPTS);
    final_bn<<<dim3(256), dim3(256), 0, stream>>>(y, g4, b4, (float*)d_out);
}

// Round 9
// 349.172 us; speedup vs baseline: 1.3062x; 1.0296x over previous
//
#include <hip/hip_runtime.h>
#include <hip/hip_bf16.h>

#define NPTS 256
#define NB   4
#define KNN  27
#define EPSV 1e-5f

typedef unsigned short u16;
typedef _Float16 f16;
typedef __attribute__((ext_vector_type(8))) _Float16 f16x8;
typedef __attribute__((ext_vector_type(4))) _Float16 f16x4;
typedef __attribute__((ext_vector_type(4))) float f32x4;
typedef __attribute__((ext_vector_type(4))) unsigned short u16x4;

// ---------------- workspace layout (bytes); ws = 256 MiB ----------------
#define OFF_IDX    0           // 110592
#define OFF_XYZ    131072      // 4*256*32*2 = 65536   f16 [b][n][32]
#define OFF_A0     262144      // 128*32*2    = 8192
#define OFF_A1     270336      // 384*96*2    = 73728
#define OFF_A2     344064      // 1536*384*2  = 1179648
#define OFF_A3     1523712     // 6144*1536*2 = 18874368
#define OFF_A4     20398080    // 256*8160*2  = 4177920
#define OFF_PQ     24576000    // f16: 3*4*6144*256*2 = 37748736 partial planes
#define OFF_SLICE  62324736    // f16: 4*6144*256*2   = 12582912 [b][2Co][n]
#define OFF_XC     74907648    // 4*256*8160*2 = 16711680  f16 [b][n][8160]
#define OFF_Y      91619328    // f16: 8*4*256*256*2 = 4194304
// end ~95.8 MB

__device__ __forceinline__ float f16_lo(unsigned w) {
    union { u16 u; f16 h; } c; c.u = (u16)(w & 0xffffu); return (float)c.h;
}
__device__ __forceinline__ float f16_hi(unsigned w) {
    union { u16 u; f16 h; } c; c.u = (u16)(w >> 16); return (float)c.h;
}
__device__ __forceinline__ u16 f16_bits(float f) {
    union { f16 h; u16 u; } c; c.h = (f16)f; return c.u;
}
__device__ __forceinline__ float f16_val(u16 u) {
    union { u16 u; f16 h; } c; c.u = u; return (float)c.h;
}

__device__ __forceinline__ float dist3_nocontract(float ax, float ay, float az,
                                                  float bx, float by, float bz) {
#pragma clang fp contract(off)
    float dx = bx - ax, dy = by - ay, dz = bz - az;
    float s = dx * dx;
    s = s + dy * dy;
    s = s + dz * dz;
    return s;
}

// ---------------- merged kNN + weight prep (one dispatch) -------------------
// blocks [0,256): kNN, 4 points/block (one per wave) + xyz f16 emit.
// blocks [256,9472): weight transform + f16 convert, one row-chunk per block.
__global__ __launch_bounds__(256) void prep_knn(
    const float* __restrict__ x, int* __restrict__ idx,
    const float* __restrict__ w0, const float* __restrict__ w1,
    const float* __restrict__ w2, const float* __restrict__ w3,
    const float* __restrict__ w4, char* __restrict__ ws)
{
    int bid = blockIdx.x;
    if (bid < 256) {
        // ---- kNN ----
        int wv = threadIdx.x >> 6;
        int lane = threadIdx.x & 63;
        int pt = bid * 4 + wv;          // 0..1023
        int b = pt >> 8, n = pt & 255;
        f16* xyz = (f16*)(ws + OFF_XYZ);

        float xp0 = x[pt * 3 + 0];
        float xp1 = x[pt * 3 + 1];
        float xp2 = x[pt * 3 + 2];

        if (lane < 32) {
            float v = (lane < 3) ? x[pt * 3 + lane] : 0.f;
            xyz[((long)b * NPTS + n) * 32 + lane] = (f16)v;
        }

        unsigned long long key[4];
#pragma unroll
        for (int u = 0; u < 4; ++u) {
            int j = lane + 64 * u;
            int gj = b * NPTS + j;
            float d = dist3_nocontract(xp0, xp1, xp2,
                                       x[gj * 3 + 0], x[gj * 3 + 1], x[gj * 3 + 2]);
            key[u] = ((unsigned long long)__float_as_uint(d) << 32) | (unsigned int)j;
        }
        for (int r = 0; r < KNN; ++r) {
            unsigned long long m = key[0];
            m = key[1] < m ? key[1] : m;
            m = key[2] < m ? key[2] : m;
            m = key[3] < m ? key[3] : m;
#pragma unroll
            for (int off = 32; off; off >>= 1) {
                unsigned long long o = __shfl_xor(m, off);
                m = o < m ? o : m;
            }
            if (lane == 0) idx[pt * KNN + r] = (int)(m & 0xffffffffu);
#pragma unroll
            for (int u = 0; u < 4; ++u)
                if (key[u] == m) key[u] = ~0ULL;
        }
        return;
    }

    // ---- weight prep ----  cumulative job blocks: 128, 512, 2048, 8192, 9216
    bid -= 256;
    const float* w;
    int r, cbase = 0, M, Co, K, Kpad, mode;
    long offA;
    if (bid < 128)      { w = w0; r = bid;        M = 96;   Co = 48;   K = 3;    Kpad = 32;   mode = 0; offA = OFF_A0; }
    else if (bid < 512) { w = w1; r = bid - 128;  M = 384;  Co = 192;  K = 96;   Kpad = 96;   mode = 0; offA = OFF_A1; }
    else if (bid < 2048){ w = w2; r = bid - 512;  M = 1536; Co = 768;  K = 384;  Kpad = 384;  mode = 0; offA = OFF_A2; }
    else if (bid < 8192){ w = w3; r = bid - 2048; M = 6144; Co = 3072; K = 1536; Kpad = 1536; mode = 0; offA = OFF_A3; }
    else { int loc = bid - 8192; w = w4; r = loc >> 2; cbase = (loc & 3) * 2048;
           M = 256; Co = 0; K = 8160; Kpad = 8160; mode = 1; offA = OFF_A4; }

    int c0 = cbase + threadIdx.x * 8;
    if (c0 >= Kpad) return;
    f16* A = (f16*)(ws + offA);

    f16x8 hv;
#pragma unroll
    for (int j = 0; j < 8; ++j) {
        int c = c0 + j;
        float a = 0.f;
        if (c < K && r < M) {
            if (mode == 1) a = w[(long)r * K + c];
            else if (r < Co) a = w[(long)r * (2 * K) + c];
            else {
                long base = (long)(r - Co) * (2 * K);
                a = w[base + K + c] - w[base + c];
            }
        }
        hv[j] = (f16)a;
    }
    *(f16x8*)&A[(long)r * Kpad + c0] = hv;
}

// ---------------- f16 MFMA GEMM, split-K into private f16 partial planes ----
// Block 128x128, BK=32; 4 waves 2x2; wave 64x64 = 4x4 tiles of
// mfma_f32_16x16x32_f16. Output stored as f16 (halves plane HBM traffic).
__global__ __launch_bounds__(256) void gemm_mfma(
    const f16* __restrict__ A, const f16* __restrict__ B,
    u16* __restrict__ out, int M, int Kpad, int K,
    int ldF, long bsF, long bsO, int nsplit, long pstride)
{
    __shared__ u16 sA[128][40], sB[128][40];

    int bz = blockIdx.z;
    int b = bz / nsplit, slice = bz - b * nsplit;
    int kchunk = (((K + nsplit - 1) / nsplit) + 31) & ~31;
    int kstart = slice * kchunk;
    int kend = K < kstart + kchunk ? K : kstart + kchunk;

    const f16* pB = B + (long)b * bsF;
    u16* Ob = out + (long)slice * pstride + (long)b * bsO;

    int m0 = blockIdx.x * 128, n0 = blockIdx.y * 128;
    int tid = threadIdx.x, lane = tid & 63, wid = tid >> 6;
    int wm = (wid >> 1) * 64, wn = (wid & 1) * 64;
    int lrow = lane & 15, quad = lane >> 4;

    int srow = tid >> 1;            // 0..127
    int sk = (tid & 1) * 16;        // 0,16

    const f16* gA = A + (long)(m0 + srow) * Kpad + sk;
    const f16* gB = pB + (long)(n0 + srow) * ldF + sk;

    f32x4 acc[4][4] = {};

    for (int kk = kstart; kk < kend; kk += 32) {
        f16x8 a0 = *(const f16x8*)(gA + kk);
        f16x8 a1 = *(const f16x8*)(gA + kk + 8);
        f16x8 b0 = *(const f16x8*)(gB + kk);
        f16x8 b1 = *(const f16x8*)(gB + kk + 8);

        __syncthreads();   // previous iteration's fragment reads complete

        *(f16x8*)&sA[srow][sk] = a0;
        *(f16x8*)&sA[srow][sk + 8] = a1;
        *(f16x8*)&sB[srow][sk] = b0;
        *(f16x8*)&sB[srow][sk + 8] = b1;

        __syncthreads();

        f16x8 fb[4];
#pragma unroll
        for (int nt = 0; nt < 4; ++nt)
            fb[nt] = *(const f16x8*)&sB[wn + nt * 16 + lrow][quad * 8];
#pragma unroll
        for (int mt = 0; mt < 4; ++mt) {
            f16x8 fa = *(const f16x8*)&sA[wm + mt * 16 + lrow][quad * 8];
#pragma unroll
            for (int nt = 0; nt < 4; ++nt)
                acc[mt][nt] = __builtin_amdgcn_mfma_f32_16x16x32_f16(fa, fb[nt], acc[mt][nt], 0, 0, 0);
        }
    }

    // epilogue: C/D layout col=lane&15, row=quad*4+reg  [m89-verified]
#pragma unroll
    for (int mt = 0; mt < 4; ++mt)
#pragma unroll
        for (int nt = 0; nt < 4; ++nt) {
            int C = n0 + wn + nt * 16 + lrow;
            int Rb = m0 + wm + mt * 16 + quad * 4;
#pragma unroll
            for (int r = 0; r < 4; ++r) {
                int R = Rb + r;
                if (R < M) Ob[(long)R * NPTS + C] = f16_bits(acc[mt][nt][r]);
            }
        }
}

// ---------------- fused gather + stats + BN/lrelu + tp concat ---------------
// Block = 4 consecutive channels x 4 batches (1 wave each). Reads f16 partial
// planes; P packed f16x4 in LDS -> 1 ds_read_b64 per k serves 4 channels.
// Writes f16 slice [b][2Co][n] (n-contiguous, coalesced).
__global__ __launch_bounds__(256, 4) void gather_finalize(
    const u16* __restrict__ PQ, long pstride, int nsplit,
    const int* __restrict__ idx,
    const float* __restrict__ g, const float* __restrict__ beta,
    u16* __restrict__ slice, int Co)
{
    __shared__ uint2 p2[NB][NPTS];      // packed f16x4 P, 8 KB
    __shared__ uint2 mxs[NB][NPTS];     // packed f16x4 per-n max, 8 KB
    __shared__ uint2 mns[NB][NPTS];     // packed f16x4 per-n min, 8 KB
    __shared__ uint2 vals[NB][NPTS];    // packed f16x4 val, 8 KB
    __shared__ float red[NB][8];
    int o0 = blockIdx.x * 4;
    int b = threadIdx.x >> 6;
    int lane = threadIdx.x & 63;

    long base_p = ((long)b * 2 * Co + o0) * NPTS;   // channel o0 P row
    long base_q = base_p + (long)Co * NPTS;         // channel o0 Q row

#pragma unroll 1
    for (int u = 0; u < 4; ++u) {
        int n = lane + 64 * u;
        u16 ph[4];
#pragma unroll
        for (int c = 0; c < 4; ++c) {
            float pv = 0.f;
            for (int sp = 0; sp < nsplit; ++sp)
                pv += f16_val(PQ[sp * pstride + base_p + c * NPTS + n]);
            ph[c] = f16_bits(pv);
        }
        uint2 pk;
        pk.x = (unsigned)ph[0] | ((unsigned)ph[1] << 16);
        pk.y = (unsigned)ph[2] | ((unsigned)ph[3] << 16);
        p2[b][n] = pk;
    }
    __syncthreads();

    float s0 = 0.f, s1 = 0.f, s2 = 0.f, s3 = 0.f;
    float t0 = 0.f, t1 = 0.f, t2 = 0.f, t3 = 0.f;
#pragma unroll 1
    for (int u = 0; u < 4; ++u) {
        int n = lane + 64 * u;
        float q0 = 0.f, q1 = 0.f, q2 = 0.f, q3 = 0.f;
        for (int sp = 0; sp < nsplit; ++sp) {
            const u16* Qp = PQ + sp * pstride + base_q + n;
            q0 += f16_val(Qp[0]);
            q1 += f16_val(Qp[NPTS]);
            q2 += f16_val(Qp[2 * NPTS]);
            q3 += f16_val(Qp[3 * NPTS]);
        }
        float mx0 = -__builtin_inff(), mx1 = mx0, mx2 = mx0, mx3 = mx0;
        float mn0 = __builtin_inff(), mn1 = mn0, mn2 = mn0, mn3 = mn0;
        const int* ip = idx + ((long)b * NPTS + n) * KNN;
#pragma unroll
        for (int k = 0; k < KNN; ++k) {
            uint2 w = p2[b][ip[k]];
            float h0 = f16_lo(w.x) + q0;
            float h1 = f16_hi(w.x) + q1;
            float h2 = f16_lo(w.y) + q2;
            float h3 = f16_hi(w.y) + q3;
            s0 += h0; t0 += h0 * h0; mx0 = fmaxf(mx0, h0); mn0 = fminf(mn0, h0);
            s1 += h1; t1 += h1 * h1; mx1 = fmaxf(mx1, h1); mn1 = fminf(mn1, h1);
            s2 += h2; t2 += h2 * h2; mx2 = fmaxf(mx2, h2); mn2 = fminf(mn2, h2);
            s3 += h3; t3 += h3 * h3; mx3 = fmaxf(mx3, h3); mn3 = fminf(mn3, h3);
        }
        uint2 mk, nk;
        mk.x = (unsigned)f16_bits(mx0) | ((unsigned)f16_bits(mx1) << 16);
        mk.y = (unsigned)f16_bits(mx2) | ((unsigned)f16_bits(mx3) << 16);
        nk.x = (unsigned)f16_bits(mn0) | ((unsigned)f16_bits(mn1) << 16);
        nk.y = (unsigned)f16_bits(mn2) | ((unsigned)f16_bits(mn3) << 16);
        mxs[b][n] = mk;
        mns[b][n] = nk;
    }
#pragma unroll
    for (int off = 32; off; off >>= 1) {
        s0 += __shfl_xor(s0, off); t0 += __shfl_xor(t0, off);
        s1 += __shfl_xor(s1, off); t1 += __shfl_xor(t1, off);
        s2 += __shfl_xor(s2, off); t2 += __shfl_xor(t2, off);
        s3 += __shfl_xor(s3, off); t3 += __shfl_xor(t3, off);
    }
    if (lane == 0) {
        red[b][0] = s0; red[b][1] = s1; red[b][2] = s2; red[b][3] = s3;
        red[b][4] = t0; red[b][5] = t1; red[b][6] = t2; red[b][7] = t3;
    }
    __syncthreads();

    const float cnt = (float)(NB * NPTS * KNN);
    float sc[4], tt[4];
#pragma unroll
    for (int c = 0; c < 4; ++c) {
        float ts = (red[0][c] + red[1][c]) + (red[2][c] + red[3][c]);
        float tss = (red[0][4 + c] + red[1][4 + c]) + (red[2][4 + c] + red[3][4 + c]);
        float mean = ts / cnt;
        float var = tss / cnt - mean * mean;
        sc[c] = g[o0 + c] * (1.0f / sqrtf(var + EPSV));
        tt[c] = beta[o0 + c] - mean * sc[c];
    }

#pragma unroll 1
    for (int u = 0; u < 4; ++u) {
        int n = lane + 64 * u;
        uint2 mk = mxs[b][n], nk = mns[b][n];
        float e0 = (sc[0] >= 0.f) ? f16_lo(mk.x) : f16_lo(nk.x);
        float e1 = (sc[1] >= 0.f) ? f16_hi(mk.x) : f16_hi(nk.x);
        float e2 = (sc[2] >= 0.f) ? f16_lo(mk.y) : f16_lo(nk.y);
        float e3 = (sc[3] >= 0.f) ? f16_hi(mk.y) : f16_hi(nk.y);
        float z0 = sc[0] * e0 + tt[0]; z0 = z0 >= 0.f ? z0 : 0.2f * z0;
        float z1 = sc[1] * e1 + tt[1]; z1 = z1 >= 0.f ? z1 : 0.2f * z1;
        float z2 = sc[2] * e2 + tt[2]; z2 = z2 >= 0.f ? z2 : 0.2f * z2;
        float z3 = sc[3] * e3 + tt[3]; z3 = z3 >= 0.f ? z3 : 0.2f * z3;
        slice[base_p + 0 * NPTS + n] = f16_bits(z0);
        slice[base_p + 1 * NPTS + n] = f16_bits(z1);
        slice[base_p + 2 * NPTS + n] = f16_bits(z2);
        slice[base_p + 3 * NPTS + n] = f16_bits(z3);
        uint2 vk;
        vk.x = (unsigned)f16_bits(z0) | ((unsigned)f16_bits(z1) << 16);
        vk.y = (unsigned)f16_bits(z2) | ((unsigned)f16_bits(z3) << 16);
        vals[b][n] = vk;
    }
    __syncthreads();

#pragma unroll 1
    for (int u = 0; u < 4; ++u) {
        int n = lane + 64 * u;
        uint2 v0 = vals[0][n], v1 = vals[1][n];
        slice[base_q + 0 * NPTS + n] = f16_bits(0.5f * (f16_lo(v0.x) + f16_lo(v1.x)));
        slice[base_q + 1 * NPTS + n] = f16_bits(0.5f * (f16_hi(v0.x) + f16_hi(v1.x)));
        slice[base_q + 2 * NPTS + n] = f16_bits(0.5f * (f16_lo(v0.y) + f16_lo(v1.y)));
        slice[base_q + 3 * NPTS + n] = f16_bits(0.5f * (f16_hi(v0.y) + f16_hi(v1.y)));
    }
}

// ---------------- transpose f16 [b][C][n] -> f16 [b][n][8160] at offc -------
__global__ __launch_bounds__(256) void transpose_cn(
    const u16* __restrict__ slice, f16* __restrict__ xc,
    int Ctot, int offc)
{
    __shared__ u16 t[32][36];
    int c0 = blockIdx.x * 32, n0 = blockIdx.y * 32, b = blockIdx.z;
    const u16* S = slice + (long)b * Ctot * NPTS;
    int tid = threadIdx.x;
    int r = tid >> 3, s4 = (tid & 7) * 4;

    u16x4 v = *(const u16x4*)&S[(long)(c0 + r) * NPTS + n0 + s4];
    t[r][s4 + 0] = v[0];
    t[r][s4 + 1] = v[1];
    t[r][s4 + 2] = v[2];
    t[r][s4 + 3] = v[3];
    __syncthreads();

    long base = ((long)b * NPTS + n0 + r) * 8160 + offc + c0 + s4;
    u16x4 hv;
#pragma unroll
    for (int j = 0; j < 4; ++j) hv[j] = t[s4 + j][r];
    *(u16x4*)&xc[base] = hv;
}

// ---------------- final BN + lrelu -> fp32 out (sums 8 f16 y planes) --------
__global__ __launch_bounds__(256) void final_bn(const u16* __restrict__ y,
                                                const float* __restrict__ g4,
                                                const float* __restrict__ b4,
                                                float* __restrict__ out) {
    __shared__ float red[8];
    int o = blockIdx.x;
    int tid = threadIdx.x;
    int lane = tid & 63, w = tid >> 6;

    float v[4];
    float s = 0.f, ss = 0.f;
#pragma unroll
    for (int b = 0; b < 4; ++b) {
        float acc = 0.f;
#pragma unroll
        for (int sp = 0; sp < 8; ++sp)
            acc += f16_val(y[sp * 262144 + b * 65536 + o * 256 + tid]);
        v[b] = acc;
        s += acc;
        ss += acc * acc;
    }
#pragma unroll
    for (int off = 32; off; off >>= 1) {
        s += __shfl_xor(s, off);
        ss += __shfl_xor(ss, off);
    }
    if (lane == 0) { red[w] = s; red[4 + w] = ss; }
    __syncthreads();
    s = (red[0] + red[1]) + (red[2] + red[3]);
    ss = (red[4] + red[5]) + (red[6] + red[7]);
    float mean = s / 1024.f;
    float var = ss / 1024.f - mean * mean;
    float sc = g4[o] * (1.0f / sqrtf(var + EPSV));
    float tt = b4[o] - mean * sc;
#pragma unroll
    for (int b = 0; b < 4; ++b) {
        float z = sc * v[b] + tt;
        z = z >= 0.f ? z : 0.2f * z;
        out[(long)b * 65536 + o * 256 + tid] = z;
    }
}

// ---------------- launch ----------------
extern "C" void kernel_launch(void* const* d_in, const int* in_sizes, int n_in,
                              void* d_out, int out_size, void* d_ws, size_t ws_size,
                              hipStream_t stream) {
    const float* x = (const float*)d_in[0];
    const float* wl[4];
    const float* gl[4];
    const float* bl[4];
    for (int i = 0; i < 4; ++i) {
        wl[i] = (const float*)d_in[1 + 3 * i];
        gl[i] = (const float*)d_in[2 + 3 * i];
        bl[i] = (const float*)d_in[3 + 3 * i];
    }
    const float* w4 = (const float*)d_in[13];
    const float* g4 = (const float*)d_in[14];
    const float* b4 = (const float*)d_in[15];

    char* ws = (char*)d_ws;
    int* idx = (int*)(ws + OFF_IDX);
    f16* xyz = (f16*)(ws + OFF_XYZ);
    u16* PQ = (u16*)(ws + OFF_PQ);
    u16* slice = (u16*)(ws + OFF_SLICE);
    f16* xc = (f16*)(ws + OFF_XC);
    u16* y = (u16*)(ws + OFF_Y);

    prep_knn<<<dim3(9472), dim3(256), 0, stream>>>(x, idx, wl[0], wl[1], wl[2], wl[3], w4, ws);

    const int Kp[4] = {32, 96, 384, 1536};     // padded K (multiples of 32)
    const int Co[4] = {48, 192, 768, 3072};
    const int offc[4] = {0, 96, 480, 2016};
    const int inoff[4] = {0, 0, 96, 480};
    const int nsp[4] = {1, 3, 4, 3};
    const long aoff[4] = {OFF_A0, OFF_A1, OFF_A2, OFF_A3};

    for (int i = 0; i < 4; ++i) {
        int M = 2 * Co[i];
        int Mpad = (M + 127) & ~127;
        const f16* A = (const f16*)(ws + aoff[i]);

        const f16* Bp;
        int ldF;
        long bsF;
        if (i == 0) { Bp = xyz; ldF = 32; bsF = (long)NPTS * 32; }
        else { Bp = xc + inoff[i]; ldF = 8160; bsF = (long)NPTS * 8160; }

        long pstride = (long)NB * M * NPTS;   // one partial plane (elements)
        gemm_mfma<<<dim3(Mpad / 128, NPTS / 128, NB * nsp[i]), dim3(256), 0, stream>>>(
            A, Bp, PQ, M, Kp[i], Kp[i], ldF, bsF, (long)M * NPTS, nsp[i], pstride);

        gather_finalize<<<dim3(Co[i] / 4), dim3(256), 0, stream>>>(
            PQ, pstride, nsp[i], idx, gl[i], bl[i], slice, Co[i]);
        transpose_cn<<<dim3(M / 32, NPTS / 32, NB), dim3(256), 0, stream>>>(
            slice, xc, M, offc[i]);
    }

    // final projection: split-K=8 into 8 private f16 y planes
    gemm_mfma<<<dim3(2, 2, NB * 8), dim3(256), 0, stream>>>(
        (const f16*)(ws + OFF_A4), xc, y, 256, 8160, 8160, 8160,
        (long)NPTS * 8160, (long)256 * NPTS, 8, (long)NB * 256 * NPTS);
    final_bn<<<dim3(256), dim3(256), 0, stream>>>(y, g4, b4, (float*)d_out);
}